// Round 7
// baseline (410.253 us; speedup 1.0000x reference)
//
#include <hip/hip_runtime.h>
#include <hip/hip_bf16.h>
#include <hip/hip_fp16.h>

#define D 64
#define GRAPHS 128

using bf16x8 = __attribute__((ext_vector_type(8))) short;   // 8 bf16 (4 VGPRs)
using f32x4  = __attribute__((ext_vector_type(4))) float;

// ---------------- small helpers ----------------

__device__ __forceinline__ float bf2f(unsigned short u) {
    return __uint_as_float(((unsigned)u) << 16);
}
__device__ __forceinline__ unsigned short f2bf(float f) {
    unsigned u = __float_as_uint(f);
    unsigned r = (u + 0x7FFFu + ((u >> 16) & 1u)) >> 16;   // RNE
    return (unsigned short)r;
}

// H layout (round 7): 8 regions of N*32 ushorts: region (slot*2 + half) holds
// features [half*32, half*32+32) of all N nodes, 64-B rows. A gather pass touches ONE
// 3.2-MB region (fits 4-MB per-XCD L2) instead of the old 6.4-MB [N][64] rows -> the
// random row reads become L2 hits after compulsory warm (r5 FETCH showed 5x re-fetch
// = capacity thrash at 6.4 MB; r3 vectorization and r4 MLP nulls are consistent).

// ---------------- pass 1: degree histogram + slot ticket (returning atomic), W/x prep ----------------
// Ticket atomic lives HERE because the W-prep and x->H blocks are co-resident and hide its
// latency (round-2 lesson: standalone returning atomics at low occupancy cost 4x).
// round-3 lesson: the 800K returning device-scope atomics execute at the coherent point --
// vectorizing around them is neutral; this pass is structural until a radix build replaces it.

__global__ void deg_prep_kernel(const int* __restrict__ dst, int* __restrict__ deg,
                                int* __restrict__ pos, int E, int EB4,
                                const float* __restrict__ W0, const float* __restrict__ W1,
                                unsigned short* __restrict__ WF0, unsigned short* __restrict__ WF1,
                                const float* __restrict__ x, unsigned short* __restrict__ H, int NH) {
    int b = blockIdx.x;
    if (b < EB4) {
        int e0 = (b * 256 + threadIdx.x) * 4;
        if (e0 + 4 <= E) {
            int4 d4 = *(const int4*)(dst + e0);
            int4 p;
            p.x = atomicAdd(&deg[d4.x], 1);
            p.y = atomicAdd(&deg[d4.y], 1);
            p.z = atomicAdd(&deg[d4.z], 1);
            p.w = atomicAdd(&deg[d4.w], 1);
            *(int4*)(pos + e0) = p;
        } else {
            for (int e = e0; e < E; ++e) pos[e] = atomicAdd(&deg[dst[e]], 1);
        }
    } else if (b < EB4 + 128) {
        // Wfrag[kt][ct][lane][j]: B[k= kt*32 + (lane>>4)*8 + j][n= ct*16 + (lane&15)]
        // K order = slot-major then feature -> matches the new region-major A layout. unchanged.
        int idx = (b - EB4) * 256 + threadIdx.x;   // 32768 = 2 * 16384
        int i = idx & 16383;
        int j = i & 7, lane = (i >> 3) & 63, ct = (i >> 9) & 3, kt = i >> 11;
        int n = ct * 16 + (lane & 15);
        int k = kt * 32 + (lane >> 4) * 8 + j;
        if (idx < 16384) WF0[i] = f2bf(W0[k * 64 + n]);
        else             WF1[i] = f2bf(W1[k * 64 + n]);
    } else {
        int i = (b - EB4 - 128) * 256 + threadIdx.x;   // i over N*8 groups of 8 feats
        if (i < NH) {
            int n = i >> 3, part = i & 7;              // part = feature octet 0..7
            size_t HS = (size_t)NH * 4;                // N*32 ushorts per region
            float4 x0 = *(const float4*)(x + (size_t)n * 64 + part * 8);
            float4 x1 = *(const float4*)(x + (size_t)n * 64 + part * 8 + 4);
            bf16x8 pk;
            pk[0] = f2bf(x0.x); pk[1] = f2bf(x0.y); pk[2] = f2bf(x0.z); pk[3] = f2bf(x0.w);
            pk[4] = f2bf(x1.x); pk[5] = f2bf(x1.y); pk[6] = f2bf(x1.z); pk[7] = f2bf(x1.w);
            *(bf16x8*)(H + (size_t)(part >> 2) * HS + (size_t)n * 32 + (part & 3) * 8) = pk;
        }
    }
}

// ---------------- pass 2: dinv + pdeg + single-pass scan (atomic block ticket) + pad fill ----------------

__global__ void scan_all_kernel(const int* __restrict__ deg, float* __restrict__ dinv,
                                int* __restrict__ pdeg, int* __restrict__ rowstart,
                                unsigned int* __restrict__ ep, int* __restrict__ total, int N) {
    __shared__ int s[256];
    __shared__ int base_sh;
    int i = blockIdx.x * 256 + threadIdx.x;
    int d = 0, p = 0;
    if (i < N) {
        d = deg[i];
        dinv[i] = d > 0 ? rsqrtf((float)d) : 0.0f;
        p = (d + 7) & ~7;
        pdeg[i] = p;
    }
    s[threadIdx.x] = p;
    __syncthreads();
    for (int st = 1; st < 256; st <<= 1) {
        int add = (threadIdx.x >= st) ? s[threadIdx.x - st] : 0;
        __syncthreads();
        s[threadIdx.x] += add;
        __syncthreads();
    }
    if (threadIdx.x == 255) base_sh = atomicAdd(total, s[255]);
    __syncthreads();
    if (i < N) {
        int excl = base_sh + s[threadIdx.x] - p;
        rowstart[i] = excl;
        for (int q = excl + d; q < excl + p; ++q) ep[q] = 0u;   // zero-weight pad
    }
}

// ---------------- pass 3: atomic-free scatter into padded CSR (4 edges/thread) ----------------

__global__ void scatter_kernel(const int* __restrict__ src, const int* __restrict__ dst,
                               const int* __restrict__ pos, const float* __restrict__ dinv,
                               const int* __restrict__ rowstart, unsigned int* __restrict__ ep, int E) {
    int e0 = (blockIdx.x * 256 + threadIdx.x) * 4;
    if (e0 + 4 <= E) {
        int4 s4 = *(const int4*)(src + e0);
        int4 d4 = *(const int4*)(dst + e0);
        int4 p4 = *(const int4*)(pos + e0);
        float v0 = dinv[s4.x], v1 = dinv[s4.y], v2 = dinv[s4.z], v3 = dinv[s4.w];
        int r0 = rowstart[d4.x], r1 = rowstart[d4.y], r2 = rowstart[d4.z], r3 = rowstart[d4.w];
        ep[r0 + p4.x] = (unsigned)s4.x | ((unsigned)__half_as_ushort(__float2half(v0)) << 16);
        ep[r1 + p4.y] = (unsigned)s4.y | ((unsigned)__half_as_ushort(__float2half(v1)) << 16);
        ep[r2 + p4.z] = (unsigned)s4.z | ((unsigned)__half_as_ushort(__float2half(v2)) << 16);
        ep[r3 + p4.w] = (unsigned)s4.w | ((unsigned)__half_as_ushort(__float2half(v3)) << 16);
    } else {
        for (int e = e0; e < E; ++e) {
            int dd = dst[e], ss = src[e];
            ep[rowstart[dd] + pos[e]] = (unsigned)ss | ((unsigned)__half_as_ushort(__float2half(dinv[ss])) << 16);
        }
    }
}

// ---------------- half-feature gather: out_half[dst] = dinv[dst] * sum_e w_e * in_half[src_e] ----------------
// One wave per (dst node, feature-half). 4 lanes/edge x bf16x8 (16 B) -> 16 edges per row-load
// instruction; random reads confined to ONE 3.2-MB region (L2-resident). ep and out use
// non-temporal hints so streaming traffic doesn't evict the hot region. Lanes with i+g >= cnt
// are predicated to ep word 0 (src 0, weight 0) -- harmless, matches the zero-pad convention.

#define GROWS 8   // 512 threads/block, 8 (node,half) jobs per block

__global__ __launch_bounds__(512, 8)
void gather_half_kernel(const unsigned short* __restrict__ in,   // region base (N*32 ushorts)
                        unsigned short* __restrict__ out,        // region base
                        const int* __restrict__ rowstart, const int* __restrict__ pdeg,
                        const float* __restrict__ dinv, const unsigned int* __restrict__ ep, int N) {
    int wid = blockIdx.x * GROWS + (threadIdx.x >> 6);
    if (wid >= N) return;
    int lane = threadIdx.x & 63;
    int g  = lane >> 2;          // edge subgroup 0..15
    int fl = (lane & 3) * 8;     // ushort offset within the 32-ushort half-row

    int start = __builtin_amdgcn_readfirstlane(rowstart[wid]);
    int cnt   = __builtin_amdgcn_readfirstlane(pdeg[wid]);    // multiple of 8
    float dd  = dinv[wid];                                    // wave-uniform

    float a0=0.f,a1=0.f,a2=0.f,a3=0.f,a4=0.f,a5=0.f,a6=0.f,a7=0.f;
    unsigned eA = 0;
    if (cnt > 0)
        eA = (g < cnt) ? __builtin_nontemporal_load(ep + start + g) : 0u;
    for (int i = 0; i < cnt; i += 16) {
        unsigned cA = eA;
        if (i + 16 < cnt)
            eA = (i + 16 + g < cnt) ? __builtin_nontemporal_load(ep + start + i + 16 + g) : 0u;
        bf16x8 rA = *(const bf16x8*)(in + (size_t)(cA & 0xFFFFu) * 32 + fl);
        float wA = __half2float(__ushort_as_half((unsigned short)(cA >> 16)));
        a0 = fmaf(wA, bf2f((unsigned short)rA[0]), a0);
        a1 = fmaf(wA, bf2f((unsigned short)rA[1]), a1);
        a2 = fmaf(wA, bf2f((unsigned short)rA[2]), a2);
        a3 = fmaf(wA, bf2f((unsigned short)rA[3]), a3);
        a4 = fmaf(wA, bf2f((unsigned short)rA[4]), a4);
        a5 = fmaf(wA, bf2f((unsigned short)rA[5]), a5);
        a6 = fmaf(wA, bf2f((unsigned short)rA[6]), a6);
        a7 = fmaf(wA, bf2f((unsigned short)rA[7]), a7);
    }
    // reduce across the 16 edge subgroups (lane bits 2..5)
    a0 += __shfl_xor(a0, 4, 64); a0 += __shfl_xor(a0, 8, 64); a0 += __shfl_xor(a0, 16, 64); a0 += __shfl_xor(a0, 32, 64);
    a1 += __shfl_xor(a1, 4, 64); a1 += __shfl_xor(a1, 8, 64); a1 += __shfl_xor(a1, 16, 64); a1 += __shfl_xor(a1, 32, 64);
    a2 += __shfl_xor(a2, 4, 64); a2 += __shfl_xor(a2, 8, 64); a2 += __shfl_xor(a2, 16, 64); a2 += __shfl_xor(a2, 32, 64);
    a3 += __shfl_xor(a3, 4, 64); a3 += __shfl_xor(a3, 8, 64); a3 += __shfl_xor(a3, 16, 64); a3 += __shfl_xor(a3, 32, 64);
    a4 += __shfl_xor(a4, 4, 64); a4 += __shfl_xor(a4, 8, 64); a4 += __shfl_xor(a4, 16, 64); a4 += __shfl_xor(a4, 32, 64);
    a5 += __shfl_xor(a5, 4, 64); a5 += __shfl_xor(a5, 8, 64); a5 += __shfl_xor(a5, 16, 64); a5 += __shfl_xor(a5, 32, 64);
    a6 += __shfl_xor(a6, 4, 64); a6 += __shfl_xor(a6, 8, 64); a6 += __shfl_xor(a6, 16, 64); a6 += __shfl_xor(a6, 32, 64);
    a7 += __shfl_xor(a7, 4, 64); a7 += __shfl_xor(a7, 8, 64); a7 += __shfl_xor(a7, 16, 64); a7 += __shfl_xor(a7, 32, 64);
    if (g == 0) {   // lanes 0..3 write the 64-B half-row
        bf16x8 pk;
        pk[0] = f2bf(a0 * dd); pk[1] = f2bf(a1 * dd);
        pk[2] = f2bf(a2 * dd); pk[3] = f2bf(a3 * dd);
        pk[4] = f2bf(a4 * dd); pk[5] = f2bf(a5 * dd);
        pk[6] = f2bf(a6 * dd); pk[7] = f2bf(a7 * dd);
        __builtin_nontemporal_store(pk, (bf16x8*)(out + (size_t)wid * 32 + fl));
    }
}

// ---------------- layer projection: C[N x 64] = H[N x 256] @ Wflat[256 x 64] ----------------
// A is read region-major: K chunk kt lives at H + kt*HS + row*32. K order (slot-major,
// feature within) is unchanged, so Wfrag is untouched.
// MODE 2: H2 = prelu(C+b) (bf16) stored region-split via LDS repack -> 16-B stores;
//         block 0 also initializes out[] = bout.
// MODE 3: pool fused: LDS bins per block (batch sorted -> ~2 graphs/block), few global atomics.

#define LROW 72   // padded LDS row (ushorts): 144 B -> 16-B aligned rows, bank-spread

template<int MODE>
__global__ __launch_bounds__(256, 4)
void tag_gemm_kernel(const unsigned short* __restrict__ H,
                     const unsigned short* __restrict__ Wfrag,
                     const float* __restrict__ bias, const float* __restrict__ alpha,
                     const float* __restrict__ Wout, const int* __restrict__ batch,
                     const float* __restrict__ bout,
                     unsigned short* __restrict__ H2, float* __restrict__ outp, int N) {
    __shared__ float bins[GRAPHS];                 // MODE 3
    __shared__ unsigned short lbuf[64 * LROW];     // MODE 2 repack buffer (9.2 KB)
    if (MODE == 3) {
        if (threadIdx.x < GRAPHS) bins[threadIdx.x] = 0.0f;
        __syncthreads();
    }
    if (MODE == 2) {
        if (blockIdx.x == 0 && threadIdx.x < GRAPHS) outp[threadIdx.x] = bout[0];
    }

    int w = threadIdx.x >> 6, lane = threadIdx.x & 63;
    int m = lane & 15, quad = lane >> 4;
    int rowbase = blockIdx.x * 64 + w * 16;
    int arow = rowbase + m;
    size_t HS = (size_t)N * 32;                    // region stride (ushorts)
    const unsigned short* abase = H + (size_t)min(arow, N - 1) * 32 + quad * 8;

    f32x4 acc0 = {0.f, 0.f, 0.f, 0.f}, acc1 = acc0, acc2 = acc0, acc3 = acc0;
#pragma unroll
    for (int kt = 0; kt < 8; ++kt) {
        bf16x8 A = *(const bf16x8*)(abase + (size_t)kt * HS);
        const unsigned short* wf = Wfrag + ((size_t)(kt * 4) * 64 + lane) * 8;
        bf16x8 B0 = *(const bf16x8*)(wf + 0 * 64 * 8);
        bf16x8 B1 = *(const bf16x8*)(wf + 1 * 64 * 8);
        bf16x8 B2 = *(const bf16x8*)(wf + 2 * 64 * 8);
        bf16x8 B3 = *(const bf16x8*)(wf + 3 * 64 * 8);
        acc0 = __builtin_amdgcn_mfma_f32_16x16x32_bf16(A, B0, acc0, 0, 0, 0);
        acc1 = __builtin_amdgcn_mfma_f32_16x16x32_bf16(A, B1, acc1, 0, 0, 0);
        acc2 = __builtin_amdgcn_mfma_f32_16x16x32_bf16(A, B2, acc2, 0, 0, 0);
        acc3 = __builtin_amdgcn_mfma_f32_16x16x32_bf16(A, B3, acc3, 0, 0, 0);
    }

    float al = alpha[0];
    f32x4 accs[4] = {acc0, acc1, acc2, acc3};
    if (MODE == 2) {
        // stage prelu(C+b) into LDS [64 rows][64 cols] (row-padded), then 16-B region stores
#pragma unroll
        for (int ct = 0; ct < 4; ++ct) {
            int col = ct * 16 + m;
            float b = bias[col];
#pragma unroll
            for (int r = 0; r < 4; ++r) {
                int lrow = w * 16 + quad * 4 + r;
                float v = accs[ct][r] + b;
                v = v >= 0.f ? v : al * v;
                lbuf[lrow * LROW + col] = f2bf(v);
            }
        }
        __syncthreads();
        // 512 chunks of 8 cols; 2 per thread; chunk part -> region part>>2
#pragma unroll
        for (int k = 0; k < 2; ++k) {
            int c = threadIdx.x * 2 + k;
            int lrow = c >> 3, part = c & 7;
            int grow = blockIdx.x * 64 + lrow;
            if (grow < N) {
                bf16x8 pk = *(const bf16x8*)(lbuf + lrow * LROW + part * 8);
                *(bf16x8*)(H2 + (size_t)(part >> 2) * HS + (size_t)grow * 32 + (part & 3) * 8) = pk;
            }
        }
    } else {
        float rv0 = 0.f, rv1 = 0.f, rv2 = 0.f, rv3 = 0.f;
#pragma unroll
        for (int ct = 0; ct < 4; ++ct) {
            int col = ct * 16 + m;
            float b = bias[col], wo = Wout[col];
            float v;
            v = accs[ct][0] + b; v = v >= 0.f ? v : al * v; rv0 = fmaf(v, wo, rv0);
            v = accs[ct][1] + b; v = v >= 0.f ? v : al * v; rv1 = fmaf(v, wo, rv1);
            v = accs[ct][2] + b; v = v >= 0.f ? v : al * v; rv2 = fmaf(v, wo, rv2);
            v = accs[ct][3] + b; v = v >= 0.f ? v : al * v; rv3 = fmaf(v, wo, rv3);
        }
        float rv[4] = {rv0, rv1, rv2, rv3};
#pragma unroll
        for (int r = 0; r < 4; ++r) {
            float v = rv[r];
            v += __shfl_xor(v, 8, 16);
            v += __shfl_xor(v, 4, 16);
            v += __shfl_xor(v, 2, 16);
            v += __shfl_xor(v, 1, 16);
            int row = rowbase + quad * 4 + r;
            if (m == 0 && row < N) atomicAdd(&bins[batch[row]], v);
        }
        __syncthreads();
        if (threadIdx.x < GRAPHS) {
            float bv = bins[threadIdx.x];
            if (bv != 0.0f) atomicAdd(&outp[threadIdx.x], bv);
        }
    }
}

extern "C" void kernel_launch(void* const* d_in, const int* in_sizes, int n_in,
                              void* d_out, int out_size, void* d_ws, size_t ws_size,
                              hipStream_t stream) {
    const float* x     = (const float*)d_in[0];
    const int*   ei    = (const int*)d_in[1];
    const int*   batch = (const int*)d_in[2];
    const float* W0    = (const float*)d_in[3];
    const float* b0    = (const float*)d_in[4];
    const float* W1    = (const float*)d_in[5];
    const float* b1    = (const float*)d_in[6];
    const float* a0    = (const float*)d_in[7];
    const float* a1    = (const float*)d_in[8];
    const float* Wout  = (const float*)d_in[9];
    const float* bout  = (const float*)d_in[10];

    const int N = in_sizes[0] / D;
    const int E = in_sizes[1] / 2;
    const int* src = ei;
    const int* dst = ei + E;

    size_t off = 0;
    auto alloc = [&](size_t bytes) -> void* {
        void* p = (char*)d_ws + off;
        off = (off + bytes + 255) & ~(size_t)255;
        return p;
    };
    const int NB = (N + 255) / 256;
    int*   deg      = (int*)alloc((size_t)(N + 1) * 4);   // deg[N] = scan ticket counter
    int*   pdeg     = (int*)alloc((size_t)N * 4);
    int*   rowstart = (int*)alloc((size_t)N * 4);
    float* dinv     = (float*)alloc((size_t)N * 4);
    int*   pos      = (int*)alloc((size_t)E * 4);
    unsigned int* epack = (unsigned int*)alloc(((size_t)E + 8ull * N) * 4);  // padded CSR, 4 B entries
    unsigned short* HA = (unsigned short*)alloc((size_t)N * 256 * 2);        // 8 regions of N*32
    unsigned short* HB = (unsigned short*)alloc((size_t)N * 256 * 2);
    unsigned short* WF0 = (unsigned short*)alloc(16384 * 2);
    unsigned short* WF1 = (unsigned short*)alloc(16384 * 2);

    const size_t HS = (size_t)N * 32;            // region stride (ushorts)
    const int EB4 = (E + 1023) / 1024;           // 4 edges/thread blocks
    const int NXH = (N * 8 + 255) / 256;         // x->H blocks (8 elems/thread)
    const int NG = (N + GROWS - 1) / GROWS;      // gather blocks (512 thr)
    const int NM = (N + 63) / 64;                // gemm blocks (256 thr)

    // --- CSR build + prep (3 kernels + memset) ---
    hipMemsetAsync(deg, 0, (size_t)(N + 1) * 4, stream);
    deg_prep_kernel<<<EB4 + 128 + NXH, 256, 0, stream>>>(dst, deg, pos, E, EB4,
                                                         W0, W1, WF0, WF1, x, HA, N * 8);
    scan_all_kernel<<<NB, 256, 0, stream>>>(deg, dinv, pdeg, rowstart, epack, deg + N, N);
    scatter_kernel<<<EB4, 256, 0, stream>>>(src, dst, pos, dinv, rowstart, epack, E);

    // --- layer 0: 3 hops x 2 half-gathers fill regions 2..7, fused GEMM+bias+PReLU -> HB ---
    for (int hop = 1; hop <= 3; ++hop) {
        gather_half_kernel<<<NG, 512, 0, stream>>>(HA + (size_t)((hop - 1) * 2 + 0) * HS,
                                                   HA + (size_t)(hop * 2 + 0) * HS,
                                                   rowstart, pdeg, dinv, epack, N);
        gather_half_kernel<<<NG, 512, 0, stream>>>(HA + (size_t)((hop - 1) * 2 + 1) * HS,
                                                   HA + (size_t)(hop * 2 + 1) * HS,
                                                   rowstart, pdeg, dinv, epack, N);
    }
    tag_gemm_kernel<2><<<NM, 256, 0, stream>>>(HA, WF0, b0, a0, nullptr, nullptr, bout,
                                               HB, (float*)d_out, N);

    // --- layer 1: same over HB, fused GEMM+bias+PReLU+Wout-dot+pool -> out ---
    for (int hop = 1; hop <= 3; ++hop) {
        gather_half_kernel<<<NG, 512, 0, stream>>>(HB + (size_t)((hop - 1) * 2 + 0) * HS,
                                                   HB + (size_t)(hop * 2 + 0) * HS,
                                                   rowstart, pdeg, dinv, epack, N);
        gather_half_kernel<<<NG, 512, 0, stream>>>(HB + (size_t)((hop - 1) * 2 + 1) * HS,
                                                   HB + (size_t)(hop * 2 + 1) * HS,
                                                   rowstart, pdeg, dinv, epack, N);
    }
    tag_gemm_kernel<3><<<NM, 256, 0, stream>>>(HB, WF1, b1, a1, Wout, batch, bout,
                                               nullptr, (float*)d_out, N);
}

// Round 8
// 281.874 us; speedup vs baseline: 1.4554x; 1.4554x over previous
//
#include <hip/hip_runtime.h>
#include <hip/hip_bf16.h>
#include <hip/hip_fp16.h>

#define D 64
#define GRAPHS 128

using bf16x8 = __attribute__((ext_vector_type(8))) short;   // 8 bf16 (4 VGPRs)
using f32x4  = __attribute__((ext_vector_type(4))) float;

// ---------------- small helpers ----------------

__device__ __forceinline__ float bf2f(unsigned short u) {
    return __uint_as_float(((unsigned)u) << 16);
}
__device__ __forceinline__ unsigned short f2bf(float f) {
    unsigned u = __float_as_uint(f);
    unsigned r = (u + 0x7FFFu + ((u >> 16) & 1u)) >> 16;   // RNE
    return (unsigned short)r;
}

// ---------------- pass 1: 8-way privatized histogram + slot ticket, W/x prep ----------------
// round-3/7 lesson: the cost of this pass is SAME-ADDRESS serialization of the returning
// ticket atomics (~16 RMW round-trips per node counter). deg8[8][N] sub-counters cut
// expected collisions per address 16 -> 2. Ticket atomic stays co-resident with the
// W-prep and x->H blocks (round-2 lesson: standalone returning atomics cost 4x).

__global__ void deg_prep_kernel(const int* __restrict__ dst, int* __restrict__ deg8,
                                int* __restrict__ pos, int E, int EB4, int N,
                                const float* __restrict__ W0, const float* __restrict__ W1,
                                unsigned short* __restrict__ WF0, unsigned short* __restrict__ WF1,
                                const float* __restrict__ x, unsigned short* __restrict__ H, int NH) {
    int b = blockIdx.x;
    if (b < EB4) {
        int e0 = (b * 256 + threadIdx.x) * 4;
        if (e0 + 4 <= E) {
            int4 d4 = *(const int4*)(dst + e0);
            int4 p;
            p.x = atomicAdd(&deg8[((e0 + 0) & 7) * N + d4.x], 1);
            p.y = atomicAdd(&deg8[((e0 + 1) & 7) * N + d4.y], 1);
            p.z = atomicAdd(&deg8[((e0 + 2) & 7) * N + d4.z], 1);
            p.w = atomicAdd(&deg8[((e0 + 3) & 7) * N + d4.w], 1);
            *(int4*)(pos + e0) = p;
        } else {
            for (int e = e0; e < E; ++e) pos[e] = atomicAdd(&deg8[(e & 7) * N + dst[e]], 1);
        }
    } else if (b < EB4 + 128) {
        // Wfrag[kt][ct][lane][j]: B[k= kt*32 + (lane>>4)*8 + j][n= ct*16 + (lane&15)]
        int idx = (b - EB4) * 256 + threadIdx.x;   // 32768 = 2 * 16384
        int i = idx & 16383;
        int j = i & 7, lane = (i >> 3) & 63, ct = (i >> 9) & 3, kt = i >> 11;
        int n = ct * 16 + (lane & 15);
        int k = kt * 32 + (lane >> 4) * 8 + j;
        if (idx < 16384) WF0[i] = f2bf(W0[k * 64 + n]);
        else             WF1[i] = f2bf(W1[k * 64 + n]);
    } else {
        int i = (b - EB4 - 128) * 256 + threadIdx.x;   // i over N*8 groups of 8 feats
        if (i < NH) {
            int n = i >> 3, f = (i & 7) * 8;
            float4 x0 = *(const float4*)(x + (size_t)n * 64 + f);
            float4 x1 = *(const float4*)(x + (size_t)n * 64 + f + 4);
            bf16x8 pk;
            pk[0] = f2bf(x0.x); pk[1] = f2bf(x0.y); pk[2] = f2bf(x0.z); pk[3] = f2bf(x0.w);
            pk[4] = f2bf(x1.x); pk[5] = f2bf(x1.y); pk[6] = f2bf(x1.z); pk[7] = f2bf(x1.w);
            *(bf16x8*)(H + (size_t)n * 256 + f) = pk;
        }
    }
}

// ---------------- pass 2: replica-sum + dinv + pdeg + scan + repbase rewrite + pad fill ----------------
// Reads the 8 replica counts (coalesced plane loads), rewrites deg8 in place as per-replica
// base offsets (exclusive prefix within the node), then the usual padded-rowstart scan.

__global__ void scan_all_kernel(int* __restrict__ deg8, float* __restrict__ dinv,
                                int* __restrict__ pdeg, int* __restrict__ rowstart,
                                unsigned int* __restrict__ ep, int* __restrict__ total, int N) {
    __shared__ int s[256];
    __shared__ int base_sh;
    int i = blockIdx.x * 256 + threadIdx.x;
    int d = 0, p = 0;
    if (i < N) {
        int run = 0;
#pragma unroll
        for (int r = 0; r < 8; ++r) {
            int c = deg8[r * N + i];
            deg8[r * N + i] = run;     // replica base (exclusive prefix)
            run += c;
        }
        d = run;
        dinv[i] = d > 0 ? rsqrtf((float)d) : 0.0f;
        p = (d + 7) & ~7;
        pdeg[i] = p;
    }
    s[threadIdx.x] = p;
    __syncthreads();
    for (int st = 1; st < 256; st <<= 1) {
        int add = (threadIdx.x >= st) ? s[threadIdx.x - st] : 0;
        __syncthreads();
        s[threadIdx.x] += add;
        __syncthreads();
    }
    if (threadIdx.x == 255) base_sh = atomicAdd(total, s[255]);
    __syncthreads();
    if (i < N) {
        int excl = base_sh + s[threadIdx.x] - p;
        rowstart[i] = excl;
        int dd = pdeg[i] - (pdeg[i] - ((pdeg[i] == 0) ? 0 : 0));  // (no-op guard)
        // recompute d from planes? d stored implicitly: pad fill uses d below
        // NOTE: d is live in registers only for i<N path above
        (void)dd;
    }
    if (i < N) {
        int excl = base_sh + s[threadIdx.x] - p;
        for (int q = excl + d; q < excl + p; ++q) ep[q] = 0u;   // zero-weight pad
    }
}

// ---------------- pass 3: atomic-free scatter into padded CSR (4 edges/thread) ----------------
// slot = rowstart[dst] + repbase[e&7][dst] + pos[e]

__global__ void scatter_kernel(const int* __restrict__ src, const int* __restrict__ dst,
                               const int* __restrict__ pos, const float* __restrict__ dinv,
                               const int* __restrict__ rowstart, const int* __restrict__ deg8,
                               unsigned int* __restrict__ ep, int E, int N) {
    int e0 = (blockIdx.x * 256 + threadIdx.x) * 4;
    if (e0 + 4 <= E) {
        int4 s4 = *(const int4*)(src + e0);
        int4 d4 = *(const int4*)(dst + e0);
        int4 p4 = *(const int4*)(pos + e0);
        float v0 = dinv[s4.x], v1 = dinv[s4.y], v2 = dinv[s4.z], v3 = dinv[s4.w];
        int r0 = rowstart[d4.x] + deg8[((e0 + 0) & 7) * N + d4.x];
        int r1 = rowstart[d4.y] + deg8[((e0 + 1) & 7) * N + d4.y];
        int r2 = rowstart[d4.z] + deg8[((e0 + 2) & 7) * N + d4.z];
        int r3 = rowstart[d4.w] + deg8[((e0 + 3) & 7) * N + d4.w];
        ep[r0 + p4.x] = (unsigned)s4.x | ((unsigned)__half_as_ushort(__float2half(v0)) << 16);
        ep[r1 + p4.y] = (unsigned)s4.y | ((unsigned)__half_as_ushort(__float2half(v1)) << 16);
        ep[r2 + p4.z] = (unsigned)s4.z | ((unsigned)__half_as_ushort(__float2half(v2)) << 16);
        ep[r3 + p4.w] = (unsigned)s4.w | ((unsigned)__half_as_ushort(__float2half(v3)) << 16);
    } else {
        for (int e = e0; e < E; ++e) {
            int dd = dst[e], ss = src[e];
            int rr = rowstart[dd] + deg8[(e & 7) * N + dd];
            ep[rr + pos[e]] = (unsigned)ss | ((unsigned)__half_as_ushort(__float2half(dinv[ss])) << 16);
        }
    }
}

// ---------------- pure gather: out_row = dinv[dst] * sum_e dinv[src_e] * in_row[src_e] ----------------
// Wave per dst node, 8 lanes/edge, bf16x8 (16 B) row load per lane; 16 edges in flight/iter.
// r3-r7 diagnosis: cost is ~fixed per random 128-B line (per-CU miss-concurrency cap);
// width/MLP/residency/occupancy levers are all null or negative. This is the structural floor.

#define GROWS 8   // 512 threads/block, 8 nodes/block

__global__ __launch_bounds__(512, 8)
void gather_kernel(const unsigned short* __restrict__ in,   // H + slot_in*64
                   unsigned short* __restrict__ out,        // H + slot_out*64
                   const int* __restrict__ rowstart, const int* __restrict__ pdeg,
                   const float* __restrict__ dinv, const unsigned int* __restrict__ ep, int N) {
    int wid = blockIdx.x * GROWS + (threadIdx.x >> 6);
    if (wid >= N) return;
    int lane = threadIdx.x & 63;
    int g  = lane >> 3;          // edge subgroup 0..7
    int fl = (lane & 7) * 8;     // feature base (8 features per lane)

    int start = __builtin_amdgcn_readfirstlane(rowstart[wid]);
    int cnt   = __builtin_amdgcn_readfirstlane(pdeg[wid]);    // multiple of 8
    float dd  = dinv[wid];                                    // wave-uniform

    float a0=0.f,a1=0.f,a2=0.f,a3=0.f,a4=0.f,a5=0.f,a6=0.f,a7=0.f;
    float c0=0.f,c1=0.f,c2=0.f,c3=0.f,c4=0.f,c5=0.f,c6=0.f,c7=0.f;
    unsigned eA = 0, eB = 0;
    if (cnt > 0) {
        eA = ep[start + g];
        eB = (8 < cnt) ? ep[start + 8 + g] : 0u;
    }
    for (int i = 0; i < cnt; i += 16) {
        unsigned cA = eA, cB = eB;
        if (i + 16 < cnt) {
            eA = ep[start + i + 16 + g];
            eB = (i + 24 < cnt) ? ep[start + i + 24 + g] : 0u;
        }
        bf16x8 rA = *(const bf16x8*)(in + (size_t)(cA & 0xFFFFu) * 256 + fl);
        bf16x8 rB = *(const bf16x8*)(in + (size_t)(cB & 0xFFFFu) * 256 + fl);
        float wA = __half2float(__ushort_as_half((unsigned short)(cA >> 16)));
        float wB = __half2float(__ushort_as_half((unsigned short)(cB >> 16)));
        a0 = fmaf(wA, bf2f((unsigned short)rA[0]), a0);
        a1 = fmaf(wA, bf2f((unsigned short)rA[1]), a1);
        a2 = fmaf(wA, bf2f((unsigned short)rA[2]), a2);
        a3 = fmaf(wA, bf2f((unsigned short)rA[3]), a3);
        a4 = fmaf(wA, bf2f((unsigned short)rA[4]), a4);
        a5 = fmaf(wA, bf2f((unsigned short)rA[5]), a5);
        a6 = fmaf(wA, bf2f((unsigned short)rA[6]), a6);
        a7 = fmaf(wA, bf2f((unsigned short)rA[7]), a7);
        c0 = fmaf(wB, bf2f((unsigned short)rB[0]), c0);
        c1 = fmaf(wB, bf2f((unsigned short)rB[1]), c1);
        c2 = fmaf(wB, bf2f((unsigned short)rB[2]), c2);
        c3 = fmaf(wB, bf2f((unsigned short)rB[3]), c3);
        c4 = fmaf(wB, bf2f((unsigned short)rB[4]), c4);
        c5 = fmaf(wB, bf2f((unsigned short)rB[5]), c5);
        c6 = fmaf(wB, bf2f((unsigned short)rB[6]), c6);
        c7 = fmaf(wB, bf2f((unsigned short)rB[7]), c7);
    }
    a0 += c0; a1 += c1; a2 += c2; a3 += c3;
    a4 += c4; a5 += c5; a6 += c6; a7 += c7;
    // reduce across the 8 edge subgroups (lane bits 3,4,5)
    a0 += __shfl_xor(a0, 8, 64); a0 += __shfl_xor(a0, 16, 64); a0 += __shfl_xor(a0, 32, 64);
    a1 += __shfl_xor(a1, 8, 64); a1 += __shfl_xor(a1, 16, 64); a1 += __shfl_xor(a1, 32, 64);
    a2 += __shfl_xor(a2, 8, 64); a2 += __shfl_xor(a2, 16, 64); a2 += __shfl_xor(a2, 32, 64);
    a3 += __shfl_xor(a3, 8, 64); a3 += __shfl_xor(a3, 16, 64); a3 += __shfl_xor(a3, 32, 64);
    a4 += __shfl_xor(a4, 8, 64); a4 += __shfl_xor(a4, 16, 64); a4 += __shfl_xor(a4, 32, 64);
    a5 += __shfl_xor(a5, 8, 64); a5 += __shfl_xor(a5, 16, 64); a5 += __shfl_xor(a5, 32, 64);
    a6 += __shfl_xor(a6, 8, 64); a6 += __shfl_xor(a6, 16, 64); a6 += __shfl_xor(a6, 32, 64);
    a7 += __shfl_xor(a7, 8, 64); a7 += __shfl_xor(a7, 16, 64); a7 += __shfl_xor(a7, 32, 64);
    if (g == 0) {
        bf16x8 pk;
        pk[0] = f2bf(a0 * dd); pk[1] = f2bf(a1 * dd);
        pk[2] = f2bf(a2 * dd); pk[3] = f2bf(a3 * dd);
        pk[4] = f2bf(a4 * dd); pk[5] = f2bf(a5 * dd);
        pk[6] = f2bf(a6 * dd); pk[7] = f2bf(a7 * dd);
        *(bf16x8*)(out + (size_t)wid * 256 + fl) = pk;
    }
}

// ---------------- layer projection: C[N x 64] = H[N x 256] @ Wflat[256 x 64] ----------------
// MODE 2: H2 = prelu(C+b) (bf16), stored via LDS repack -> bf16x8 16-B stores;
//         block 0 also initializes out[] = bout.
// MODE 3: pool fused: LDS bins per block (batch sorted -> ~2 graphs/block), few global atomics.

#define LROW 72   // padded LDS row (ushorts): 144 B -> 16-B aligned rows, bank-spread

template<int MODE>
__global__ __launch_bounds__(256, 4)
void tag_gemm_kernel(const unsigned short* __restrict__ H,
                     const unsigned short* __restrict__ Wfrag,
                     const float* __restrict__ bias, const float* __restrict__ alpha,
                     const float* __restrict__ Wout, const int* __restrict__ batch,
                     const float* __restrict__ bout,
                     unsigned short* __restrict__ H2, float* __restrict__ outp, int N) {
    __shared__ float bins[GRAPHS];                 // MODE 3
    __shared__ unsigned short lbuf[64 * LROW];     // MODE 2 repack buffer (9.2 KB)
    if (MODE == 3) {
        if (threadIdx.x < GRAPHS) bins[threadIdx.x] = 0.0f;
        __syncthreads();
    }
    if (MODE == 2) {
        if (blockIdx.x == 0 && threadIdx.x < GRAPHS) outp[threadIdx.x] = bout[0];
    }

    int w = threadIdx.x >> 6, lane = threadIdx.x & 63;
    int m = lane & 15, quad = lane >> 4;
    int rowbase = blockIdx.x * 64 + w * 16;
    int arow = rowbase + m;
    size_t aoff = (size_t)min(arow, N - 1) * 256 + quad * 8;

    f32x4 acc0 = {0.f, 0.f, 0.f, 0.f}, acc1 = acc0, acc2 = acc0, acc3 = acc0;
#pragma unroll
    for (int kt = 0; kt < 8; ++kt) {
        bf16x8 A = *(const bf16x8*)(H + aoff + kt * 32);
        const unsigned short* wf = Wfrag + ((size_t)(kt * 4) * 64 + lane) * 8;
        bf16x8 B0 = *(const bf16x8*)(wf + 0 * 64 * 8);
        bf16x8 B1 = *(const bf16x8*)(wf + 1 * 64 * 8);
        bf16x8 B2 = *(const bf16x8*)(wf + 2 * 64 * 8);
        bf16x8 B3 = *(const bf16x8*)(wf + 3 * 64 * 8);
        acc0 = __builtin_amdgcn_mfma_f32_16x16x32_bf16(A, B0, acc0, 0, 0, 0);
        acc1 = __builtin_amdgcn_mfma_f32_16x16x32_bf16(A, B1, acc1, 0, 0, 0);
        acc2 = __builtin_amdgcn_mfma_f32_16x16x32_bf16(A, B2, acc2, 0, 0, 0);
        acc3 = __builtin_amdgcn_mfma_f32_16x16x32_bf16(A, B3, acc3, 0, 0, 0);
    }

    float al = alpha[0];
    f32x4 accs[4] = {acc0, acc1, acc2, acc3};
    if (MODE == 2) {
        // stage prelu(C+b) into LDS [64 rows][64 cols] (row-padded), then 16-B stores
#pragma unroll
        for (int ct = 0; ct < 4; ++ct) {
            int col = ct * 16 + m;
            float b = bias[col];
#pragma unroll
            for (int r = 0; r < 4; ++r) {
                int lrow = w * 16 + quad * 4 + r;
                float v = accs[ct][r] + b;
                v = v >= 0.f ? v : al * v;
                lbuf[lrow * LROW + col] = f2bf(v);
            }
        }
        __syncthreads();
        // 512 chunks of 8 cols; 2 per thread
#pragma unroll
        for (int k = 0; k < 2; ++k) {
            int c = threadIdx.x * 2 + k;
            int lrow = c >> 3, part = c & 7;
            int grow = blockIdx.x * 64 + lrow;
            if (grow < N) {
                bf16x8 pk = *(const bf16x8*)(lbuf + lrow * LROW + part * 8);
                *(bf16x8*)(H2 + (size_t)grow * 256 + part * 8) = pk;
            }
        }
    } else {
        float rv0 = 0.f, rv1 = 0.f, rv2 = 0.f, rv3 = 0.f;
#pragma unroll
        for (int ct = 0; ct < 4; ++ct) {
            int col = ct * 16 + m;
            float b = bias[col], wo = Wout[col];
            float v;
            v = accs[ct][0] + b; v = v >= 0.f ? v : al * v; rv0 = fmaf(v, wo, rv0);
            v = accs[ct][1] + b; v = v >= 0.f ? v : al * v; rv1 = fmaf(v, wo, rv1);
            v = accs[ct][2] + b; v = v >= 0.f ? v : al * v; rv2 = fmaf(v, wo, rv2);
            v = accs[ct][3] + b; v = v >= 0.f ? v : al * v; rv3 = fmaf(v, wo, rv3);
        }
        float rv[4] = {rv0, rv1, rv2, rv3};
#pragma unroll
        for (int r = 0; r < 4; ++r) {
            float v = rv[r];
            v += __shfl_xor(v, 8, 16);
            v += __shfl_xor(v, 4, 16);
            v += __shfl_xor(v, 2, 16);
            v += __shfl_xor(v, 1, 16);
            int row = rowbase + quad * 4 + r;
            if (m == 0 && row < N) atomicAdd(&bins[batch[row]], v);
        }
        __syncthreads();
        if (threadIdx.x < GRAPHS) {
            float bv = bins[threadIdx.x];
            if (bv != 0.0f) atomicAdd(&outp[threadIdx.x], bv);
        }
    }
}

extern "C" void kernel_launch(void* const* d_in, const int* in_sizes, int n_in,
                              void* d_out, int out_size, void* d_ws, size_t ws_size,
                              hipStream_t stream) {
    const float* x     = (const float*)d_in[0];
    const int*   ei    = (const int*)d_in[1];
    const int*   batch = (const int*)d_in[2];
    const float* W0    = (const float*)d_in[3];
    const float* b0    = (const float*)d_in[4];
    const float* W1    = (const float*)d_in[5];
    const float* b1    = (const float*)d_in[6];
    const float* a0    = (const float*)d_in[7];
    const float* a1    = (const float*)d_in[8];
    const float* Wout  = (const float*)d_in[9];
    const float* bout  = (const float*)d_in[10];

    const int N = in_sizes[0] / D;
    const int E = in_sizes[1] / 2;
    const int* src = ei;
    const int* dst = ei + E;

    size_t off = 0;
    auto alloc = [&](size_t bytes) -> void* {
        void* p = (char*)d_ws + off;
        off = (off + bytes + 255) & ~(size_t)255;
        return p;
    };
    const int NB = (N + 255) / 256;
    int*   deg8     = (int*)alloc(((size_t)N * 8 + 1) * 4); // 8 replica planes + scan ticket
    int*   pdeg     = (int*)alloc((size_t)N * 4);
    int*   rowstart = (int*)alloc((size_t)N * 4);
    float* dinv     = (float*)alloc((size_t)N * 4);
    int*   pos      = (int*)alloc((size_t)E * 4);
    unsigned int* epack = (unsigned int*)alloc(((size_t)E + 8ull * N) * 4);  // padded CSR, 4 B entries
    unsigned short* HA = (unsigned short*)alloc((size_t)N * 256 * 2);        // [N][4][64] bf16
    unsigned short* HB = (unsigned short*)alloc((size_t)N * 256 * 2);
    unsigned short* WF0 = (unsigned short*)alloc(16384 * 2);
    unsigned short* WF1 = (unsigned short*)alloc(16384 * 2);

    const int EB4 = (E + 1023) / 1024;           // 4 edges/thread blocks
    const int NXH = (N * 8 + 255) / 256;         // x->H blocks (8 elems/thread)
    const int NG = (N + GROWS - 1) / GROWS;      // gather blocks (512 thr)
    const int NM = (N + 63) / 64;                // gemm blocks (256 thr)

    // --- CSR build + prep (3 kernels + memset) ---
    hipMemsetAsync(deg8, 0, ((size_t)N * 8 + 1) * 4, stream);
    deg_prep_kernel<<<EB4 + 128 + NXH, 256, 0, stream>>>(dst, deg8, pos, E, EB4, N,
                                                         W0, W1, WF0, WF1, x, HA, N * 8);
    scan_all_kernel<<<NB, 256, 0, stream>>>(deg8, dinv, pdeg, rowstart, epack, deg8 + (size_t)N * 8, N);
    scatter_kernel<<<EB4, 256, 0, stream>>>(src, dst, pos, dinv, rowstart, deg8, epack, E, N);

    // --- layer 0: gathers fill HA slots 1..3, fused GEMM+bias+PReLU -> HB slot 0 (+ out init) ---
    gather_kernel<<<NG, 512, 0, stream>>>(HA + 0 * 64, HA + 1 * 64, rowstart, pdeg, dinv, epack, N);
    gather_kernel<<<NG, 512, 0, stream>>>(HA + 1 * 64, HA + 2 * 64, rowstart, pdeg, dinv, epack, N);
    gather_kernel<<<NG, 512, 0, stream>>>(HA + 2 * 64, HA + 3 * 64, rowstart, pdeg, dinv, epack, N);
    tag_gemm_kernel<2><<<NM, 256, 0, stream>>>(HA, WF0, b0, a0, nullptr, nullptr, bout,
                                               HB, (float*)d_out, N);

    // --- layer 1: gathers fill HB slots 1..3, fused GEMM+bias+PReLU+Wout-dot+pool -> out ---
    gather_kernel<<<NG, 512, 0, stream>>>(HB + 0 * 64, HB + 1 * 64, rowstart, pdeg, dinv, epack, N);
    gather_kernel<<<NG, 512, 0, stream>>>(HB + 1 * 64, HB + 2 * 64, rowstart, pdeg, dinv, epack, N);
    gather_kernel<<<NG, 512, 0, stream>>>(HB + 2 * 64, HB + 3 * 64, rowstart, pdeg, dinv, epack, N);
    tag_gemm_kernel<3><<<NM, 256, 0, stream>>>(HB, WF1, b1, a1, Wout, batch, bout,
                                               nullptr, (float*)d_out, N);
}

// Round 10
// 257.259 us; speedup vs baseline: 1.5947x; 1.0957x over previous
//
#include <hip/hip_runtime.h>
#include <hip/hip_bf16.h>
#include <hip/hip_fp16.h>

#define D 64
#define GRAPHS 128

using bf16x8 = __attribute__((ext_vector_type(8))) short;   // 8 bf16 (4 VGPRs)
using f32x4  = __attribute__((ext_vector_type(4))) float;

// ---------------- small helpers ----------------

__device__ __forceinline__ float bf2f(unsigned short u) {
    return __uint_as_float(((unsigned)u) << 16);
}
__device__ __forceinline__ unsigned short f2bf(float f) {
    unsigned u = __float_as_uint(f);
    unsigned r = (u + 0x7FFFu + ((u >> 16) & 1u)) >> 16;   // RNE
    return (unsigned short)r;
}

// ================= CSR build: 3-phase bucket sort (round 10) =================
// r9 bug: one-pass bucketing has no valid global slot until bucket totals are
// scanned. Correct structure: count -> scan -> scatter. gcount/gcursor are
// line-padded (stride 32 ints = 128 B) so hot-counter RMWs hit distinct lines.

// ---- pass 1: bucket-count (fire-and-forget) + W/x prep ----

__global__ void prep_kernel(const int* __restrict__ dst, int* __restrict__ gcount,
                            int E, int B1,
                            const float* __restrict__ W0, const float* __restrict__ W1,
                            unsigned short* __restrict__ WF0, unsigned short* __restrict__ WF1,
                            const float* __restrict__ x, unsigned short* __restrict__ H, int NH) {
    int b = blockIdx.x;
    if (b < B1) {
        __shared__ int hist[256];
        int t = threadIdx.x;
        hist[t] = 0;
        __syncthreads();
        int e0 = b * 2048 + t;
#pragma unroll
        for (int r = 0; r < 8; ++r) {
            int e = e0 + r * 256;
            if (e < E) atomicAdd(&hist[dst[e] >> 8], 1);
        }
        __syncthreads();
        if (hist[t]) atomicAdd(&gcount[t * 32], hist[t]);   // no return use
    } else if (b < B1 + 128) {
        // Wfrag[kt][ct][lane][j]: B[k= kt*32 + (lane>>4)*8 + j][n= ct*16 + (lane&15)]
        int idx = (b - B1) * 256 + threadIdx.x;   // 32768 = 2 * 16384
        int i = idx & 16383;
        int j = i & 7, lane = (i >> 3) & 63, ct = (i >> 9) & 3, kt = i >> 11;
        int n = ct * 16 + (lane & 15);
        int k = kt * 32 + (lane >> 4) * 8 + j;
        if (idx < 16384) WF0[i] = f2bf(W0[k * 64 + n]);
        else             WF1[i] = f2bf(W1[k * 64 + n]);
    } else {
        int i = (b - B1 - 128) * 256 + threadIdx.x;   // i over N*8 groups of 8 feats
        if (i < NH) {
            int n = i >> 3, f = (i & 7) * 8;
            float4 x0 = *(const float4*)(x + (size_t)n * 64 + f);
            float4 x1 = *(const float4*)(x + (size_t)n * 64 + f + 4);
            bf16x8 pk;
            pk[0] = f2bf(x0.x); pk[1] = f2bf(x0.y); pk[2] = f2bf(x0.z); pk[3] = f2bf(x0.w);
            pk[4] = f2bf(x1.x); pk[5] = f2bf(x1.y); pk[6] = f2bf(x1.z); pk[7] = f2bf(x1.w);
            *(bf16x8*)(H + (size_t)n * 256 + f) = pk;
        }
    }
}

// ---- pass 2: 256-entry exclusive scan -> gbase[257], init gcursor ----

__global__ void scan256_kernel(const int* __restrict__ gcount, int* __restrict__ gbase,
                               int* __restrict__ gcursor, int E) {
    __shared__ int s[256];
    int t = threadIdx.x;
    int c = gcount[t * 32];
    s[t] = c;
    __syncthreads();
    for (int st = 1; st < 256; st <<= 1) {
        int add = (t >= st) ? s[t - st] : 0;
        __syncthreads();
        s[t] += add;
        __syncthreads();
    }
    int excl = s[t] - c;
    gbase[t] = excl;
    gcursor[t * 32] = excl;
    if (t == 255) gbase[256] = E;
}

// ---- pass 3: bucket scatter with global cursors ----

__global__ void bucket_kernel(const int* __restrict__ dst, const int* __restrict__ src,
                              int* __restrict__ gcursor, unsigned int* __restrict__ tmp32, int E) {
    __shared__ int hist[256];
    __shared__ int basec[256];
    int t = threadIdx.x, b = blockIdx.x;
    hist[t] = 0;
    __syncthreads();
    unsigned pk[8];
    int bk[8];
    int e0 = b * 2048 + t;
#pragma unroll
    for (int r = 0; r < 8; ++r) {
        int e = e0 + r * 256;
        if (e < E) {
            int d = dst[e];
            pk[r] = ((unsigned)d << 16) | (unsigned)src[e];
            bk[r] = d >> 8;
            atomicAdd(&hist[bk[r]], 1);
        } else bk[r] = -1;
    }
    __syncthreads();
    if (hist[t]) basec[t] = atomicAdd(&gcursor[t * 32], hist[t]);   // GLOBAL base
    __syncthreads();
#pragma unroll
    for (int r = 0; r < 8; ++r) {
        if (bk[r] >= 0) {
            int slot = atomicAdd(&basec[bk[r]], 1);
            tmp32[slot] = pk[r];
        }
    }
}

// ---- pass 4: in-bucket grouping by dst low byte; per-node deg/rowstart/dinv free ----
// 512 threads/block, one block per high bucket (~4096 elems). ep gets src-only entries.

__global__ __launch_bounds__(512)
void radix2_kernel(const int* __restrict__ gbase, const unsigned int* __restrict__ tmp32,
                   unsigned int* __restrict__ ep, float* __restrict__ dinv,
                   int* __restrict__ pdeg, int* __restrict__ rowstart, int N) {
    __shared__ int s[256];
    __shared__ int hist[256];
    __shared__ int cur[256];
    int h = blockIdx.x, t = threadIdx.x;
    int start = gbase[h];
    int cnt   = gbase[h + 1] - start;

    if (t < 256) hist[t] = 0;
    __syncthreads();
    for (int j = t; j < cnt; j += 512)
        atomicAdd(&hist[(tmp32[start + j] >> 16) & 0xFF], 1);
    __syncthreads();

    int myc = (t < 256) ? hist[t] : 0;
    if (t < 256) s[t] = myc;
    __syncthreads();
    for (int st = 1; st < 256; st <<= 1) {
        int add = (t < 256 && t >= st) ? s[t - st] : 0;
        __syncthreads();
        if (t < 256) s[t] += add;
        __syncthreads();
    }
    if (t < 256) {
        int excl = s[t] - myc;
        int node = h * 256 + t;
        if (node < N) {
            pdeg[node] = myc;                       // raw degree
            rowstart[node] = start + excl;
            dinv[node] = myc > 0 ? rsqrtf((float)myc) : 0.0f;
        }
        cur[t] = excl;
    }
    __syncthreads();

    for (int j = t; j < cnt; j += 512) {
        unsigned v = tmp32[start + j];
        int lo = (v >> 16) & 0xFF;
        int r = atomicAdd(&cur[lo], 1);
        ep[start + r] = v & 0xFFFFu;
    }
}

// ---- pass 5: pack w = f16(dinv[src]) into ep (after radix2: dinv[src] crosses buckets) ----

__global__ void wfix_kernel(unsigned int* __restrict__ ep, const float* __restrict__ dinv, int E) {
    int e0 = (blockIdx.x * 256 + threadIdx.x) * 4;
    if (e0 + 4 <= E) {
        uint4 v = *(const uint4*)(ep + e0);
        unsigned w0 = __half_as_ushort(__float2half(dinv[v.x]));
        unsigned w1 = __half_as_ushort(__float2half(dinv[v.y]));
        unsigned w2 = __half_as_ushort(__float2half(dinv[v.z]));
        unsigned w3 = __half_as_ushort(__float2half(dinv[v.w]));
        v.x |= w0 << 16; v.y |= w1 << 16; v.z |= w2 << 16; v.w |= w3 << 16;
        *(uint4*)(ep + e0) = v;
    } else {
        for (int e = e0; e < E; ++e) {
            unsigned v = ep[e];
            v |= (unsigned)__half_as_ushort(__float2half(dinv[v])) << 16;
            ep[e] = v;
        }
    }
}

// ---------------- pure gather: out_row = dinv[dst] * sum_e dinv[src_e] * in_row[src_e] ----------------
// Wave per dst node, 8 lanes/edge, bf16x8 (16 B) row load per lane; 16 edges in flight/iter.
// cnt is raw degree: per-lane predication; pred-off lanes read hot row 0 with w=0.
// r3-r7: cost is ~fixed per random line (per-CU transaction cap) -- structural floor.

#define GROWS 8   // 512 threads/block, 8 nodes/block

__global__ __launch_bounds__(512, 8)
void gather_kernel(const unsigned short* __restrict__ in,   // H + slot_in*64
                   unsigned short* __restrict__ out,        // H + slot_out*64
                   const int* __restrict__ rowstart, const int* __restrict__ pdeg,
                   const float* __restrict__ dinv, const unsigned int* __restrict__ ep, int N) {
    int wid = blockIdx.x * GROWS + (threadIdx.x >> 6);
    if (wid >= N) return;
    int lane = threadIdx.x & 63;
    int g  = lane >> 3;          // edge subgroup 0..7
    int fl = (lane & 7) * 8;     // feature base (8 features per lane)

    int start = __builtin_amdgcn_readfirstlane(rowstart[wid]);
    int cnt   = __builtin_amdgcn_readfirstlane(pdeg[wid]);    // raw degree
    float dd  = dinv[wid];                                    // wave-uniform

    float a0=0.f,a1=0.f,a2=0.f,a3=0.f,a4=0.f,a5=0.f,a6=0.f,a7=0.f;
    float c0=0.f,c1=0.f,c2=0.f,c3=0.f,c4=0.f,c5=0.f,c6=0.f,c7=0.f;
    unsigned eA = 0, eB = 0;
    if (cnt > 0) {
        eA = (g < cnt) ? ep[start + g] : 0u;
        eB = (8 + g < cnt) ? ep[start + 8 + g] : 0u;
    }
    for (int i = 0; i < cnt; i += 16) {
        unsigned cA = eA, cB = eB;
        if (i + 16 < cnt) {
            eA = (i + 16 + g < cnt) ? ep[start + i + 16 + g] : 0u;
            eB = (i + 24 + g < cnt) ? ep[start + i + 24 + g] : 0u;
        }
        bf16x8 rA = *(const bf16x8*)(in + (size_t)(cA & 0xFFFFu) * 256 + fl);
        bf16x8 rB = *(const bf16x8*)(in + (size_t)(cB & 0xFFFFu) * 256 + fl);
        float wA = __half2float(__ushort_as_half((unsigned short)(cA >> 16)));
        float wB = __half2float(__ushort_as_half((unsigned short)(cB >> 16)));
        a0 = fmaf(wA, bf2f((unsigned short)rA[0]), a0);
        a1 = fmaf(wA, bf2f((unsigned short)rA[1]), a1);
        a2 = fmaf(wA, bf2f((unsigned short)rA[2]), a2);
        a3 = fmaf(wA, bf2f((unsigned short)rA[3]), a3);
        a4 = fmaf(wA, bf2f((unsigned short)rA[4]), a4);
        a5 = fmaf(wA, bf2f((unsigned short)rA[5]), a5);
        a6 = fmaf(wA, bf2f((unsigned short)rA[6]), a6);
        a7 = fmaf(wA, bf2f((unsigned short)rA[7]), a7);
        c0 = fmaf(wB, bf2f((unsigned short)rB[0]), c0);
        c1 = fmaf(wB, bf2f((unsigned short)rB[1]), c1);
        c2 = fmaf(wB, bf2f((unsigned short)rB[2]), c2);
        c3 = fmaf(wB, bf2f((unsigned short)rB[3]), c3);
        c4 = fmaf(wB, bf2f((unsigned short)rB[4]), c4);
        c5 = fmaf(wB, bf2f((unsigned short)rB[5]), c5);
        c6 = fmaf(wB, bf2f((unsigned short)rB[6]), c6);
        c7 = fmaf(wB, bf2f((unsigned short)rB[7]), c7);
    }
    a0 += c0; a1 += c1; a2 += c2; a3 += c3;
    a4 += c4; a5 += c5; a6 += c6; a7 += c7;
    // reduce across the 8 edge subgroups (lane bits 3,4,5)
    a0 += __shfl_xor(a0, 8, 64); a0 += __shfl_xor(a0, 16, 64); a0 += __shfl_xor(a0, 32, 64);
    a1 += __shfl_xor(a1, 8, 64); a1 += __shfl_xor(a1, 16, 64); a1 += __shfl_xor(a1, 32, 64);
    a2 += __shfl_xor(a2, 8, 64); a2 += __shfl_xor(a2, 16, 64); a2 += __shfl_xor(a2, 32, 64);
    a3 += __shfl_xor(a3, 8, 64); a3 += __shfl_xor(a3, 16, 64); a3 += __shfl_xor(a3, 32, 64);
    a4 += __shfl_xor(a4, 8, 64); a4 += __shfl_xor(a4, 16, 64); a4 += __shfl_xor(a4, 32, 64);
    a5 += __shfl_xor(a5, 8, 64); a5 += __shfl_xor(a5, 16, 64); a5 += __shfl_xor(a5, 32, 64);
    a6 += __shfl_xor(a6, 8, 64); a6 += __shfl_xor(a6, 16, 64); a6 += __shfl_xor(a6, 32, 64);
    a7 += __shfl_xor(a7, 8, 64); a7 += __shfl_xor(a7, 16, 64); a7 += __shfl_xor(a7, 32, 64);
    if (g == 0) {
        bf16x8 pk;
        pk[0] = f2bf(a0 * dd); pk[1] = f2bf(a1 * dd);
        pk[2] = f2bf(a2 * dd); pk[3] = f2bf(a3 * dd);
        pk[4] = f2bf(a4 * dd); pk[5] = f2bf(a5 * dd);
        pk[6] = f2bf(a6 * dd); pk[7] = f2bf(a7 * dd);
        *(bf16x8*)(out + (size_t)wid * 256 + fl) = pk;
    }
}

// ---------------- layer projection: C[N x 64] = H[N x 256] @ Wflat[256 x 64] ----------------
// MODE 2: H2 = prelu(C+b) (bf16), stored via LDS repack -> bf16x8 16-B stores;
//         block 0 also initializes out[] = bout.
// MODE 3: pool fused: LDS bins per block (batch sorted -> ~2 graphs/block), few global atomics.

#define LROW 72   // padded LDS row (ushorts): 144 B -> 16-B aligned rows, bank-spread

template<int MODE>
__global__ __launch_bounds__(256, 4)
void tag_gemm_kernel(const unsigned short* __restrict__ H,
                     const unsigned short* __restrict__ Wfrag,
                     const float* __restrict__ bias, const float* __restrict__ alpha,
                     const float* __restrict__ Wout, const int* __restrict__ batch,
                     const float* __restrict__ bout,
                     unsigned short* __restrict__ H2, float* __restrict__ outp, int N) {
    __shared__ float bins[GRAPHS];                 // MODE 3
    __shared__ unsigned short lbuf[64 * LROW];     // MODE 2 repack buffer (9.2 KB)
    if (MODE == 3) {
        if (threadIdx.x < GRAPHS) bins[threadIdx.x] = 0.0f;
        __syncthreads();
    }
    if (MODE == 2) {
        if (blockIdx.x == 0 && threadIdx.x < GRAPHS) outp[threadIdx.x] = bout[0];
    }

    int w = threadIdx.x >> 6, lane = threadIdx.x & 63;
    int m = lane & 15, quad = lane >> 4;
    int rowbase = blockIdx.x * 64 + w * 16;
    int arow = rowbase + m;
    size_t aoff = (size_t)min(arow, N - 1) * 256 + quad * 8;

    f32x4 acc0 = {0.f, 0.f, 0.f, 0.f}, acc1 = acc0, acc2 = acc0, acc3 = acc0;
#pragma unroll
    for (int kt = 0; kt < 8; ++kt) {
        bf16x8 A = *(const bf16x8*)(H + aoff + kt * 32);
        const unsigned short* wf = Wfrag + ((size_t)(kt * 4) * 64 + lane) * 8;
        bf16x8 B0 = *(const bf16x8*)(wf + 0 * 64 * 8);
        bf16x8 B1 = *(const bf16x8*)(wf + 1 * 64 * 8);
        bf16x8 B2 = *(const bf16x8*)(wf + 2 * 64 * 8);
        bf16x8 B3 = *(const bf16x8*)(wf + 3 * 64 * 8);
        acc0 = __builtin_amdgcn_mfma_f32_16x16x32_bf16(A, B0, acc0, 0, 0, 0);
        acc1 = __builtin_amdgcn_mfma_f32_16x16x32_bf16(A, B1, acc1, 0, 0, 0);
        acc2 = __builtin_amdgcn_mfma_f32_16x16x32_bf16(A, B2, acc2, 0, 0, 0);
        acc3 = __builtin_amdgcn_mfma_f32_16x16x32_bf16(A, B3, acc3, 0, 0, 0);
    }

    float al = alpha[0];
    f32x4 accs[4] = {acc0, acc1, acc2, acc3};
    if (MODE == 2) {
        // stage prelu(C+b) into LDS [64 rows][64 cols] (row-padded), then 16-B stores
#pragma unroll
        for (int ct = 0; ct < 4; ++ct) {
            int col = ct * 16 + m;
            float b = bias[col];
#pragma unroll
            for (int r = 0; r < 4; ++r) {
                int lrow = w * 16 + quad * 4 + r;
                float v = accs[ct][r] + b;
                v = v >= 0.f ? v : al * v;
                lbuf[lrow * LROW + col] = f2bf(v);
            }
        }
        __syncthreads();
        // 512 chunks of 8 cols; 2 per thread
#pragma unroll
        for (int k = 0; k < 2; ++k) {
            int c = threadIdx.x * 2 + k;
            int lrow = c >> 3, part = c & 7;
            int grow = blockIdx.x * 64 + lrow;
            if (grow < N) {
                bf16x8 pk = *(const bf16x8*)(lbuf + lrow * LROW + part * 8);
                *(bf16x8*)(H2 + (size_t)grow * 256 + part * 8) = pk;
            }
        }
    } else {
        float rv0 = 0.f, rv1 = 0.f, rv2 = 0.f, rv3 = 0.f;
#pragma unroll
        for (int ct = 0; ct < 4; ++ct) {
            int col = ct * 16 + m;
            float b = bias[col], wo = Wout[col];
            float v;
            v = accs[ct][0] + b; v = v >= 0.f ? v : al * v; rv0 = fmaf(v, wo, rv0);
            v = accs[ct][1] + b; v = v >= 0.f ? v : al * v; rv1 = fmaf(v, wo, rv1);
            v = accs[ct][2] + b; v = v >= 0.f ? v : al * v; rv2 = fmaf(v, wo, rv2);
            v = accs[ct][3] + b; v = v >= 0.f ? v : al * v; rv3 = fmaf(v, wo, rv3);
        }
        float rv[4] = {rv0, rv1, rv2, rv3};
#pragma unroll
        for (int r = 0; r < 4; ++r) {
            float v = rv[r];
            v += __shfl_xor(v, 8, 16);
            v += __shfl_xor(v, 4, 16);
            v += __shfl_xor(v, 2, 16);
            v += __shfl_xor(v, 1, 16);
            int row = rowbase + quad * 4 + r;
            if (m == 0 && row < N) atomicAdd(&bins[batch[row]], v);
        }
        __syncthreads();
        if (threadIdx.x < GRAPHS) {
            float bv = bins[threadIdx.x];
            if (bv != 0.0f) atomicAdd(&outp[threadIdx.x], bv);
        }
    }
}

extern "C" void kernel_launch(void* const* d_in, const int* in_sizes, int n_in,
                              void* d_out, int out_size, void* d_ws, size_t ws_size,
                              hipStream_t stream) {
    const float* x     = (const float*)d_in[0];
    const int*   ei    = (const int*)d_in[1];
    const int*   batch = (const int*)d_in[2];
    const float* W0    = (const float*)d_in[3];
    const float* b0    = (const float*)d_in[4];
    const float* W1    = (const float*)d_in[5];
    const float* b1    = (const float*)d_in[6];
    const float* a0    = (const float*)d_in[7];
    const float* a1    = (const float*)d_in[8];
    const float* Wout  = (const float*)d_in[9];
    const float* bout  = (const float*)d_in[10];

    const int N = in_sizes[0] / D;
    const int E = in_sizes[1] / 2;
    const int* src = ei;
    const int* dst = ei + E;

    size_t off = 0;
    auto alloc = [&](size_t bytes) -> void* {
        void* p = (char*)d_ws + off;
        off = (off + bytes + 255) & ~(size_t)255;
        return p;
    };
    int*   gcount   = (int*)alloc(256 * 32 * 4);          // line-padded bucket counts
    int*   gcursor  = (int*)alloc(256 * 32 * 4);          // line-padded global cursors
    int*   gbase    = (int*)alloc(257 * 4);               // bucket bases (+ sentinel E)
    int*   pdeg     = (int*)alloc((size_t)N * 4);         // raw degrees
    int*   rowstart = (int*)alloc((size_t)N * 4);
    float* dinv     = (float*)alloc((size_t)N * 4);
    unsigned int* tmp32 = (unsigned int*)alloc((size_t)E * 4);   // bucketed (dst<<16|src)
    unsigned int* epack = (unsigned int*)alloc((size_t)E * 4);   // final CSR entries
    unsigned short* HA = (unsigned short*)alloc((size_t)N * 256 * 2);   // [N][4][64] bf16
    unsigned short* HB = (unsigned short*)alloc((size_t)N * 256 * 2);
    unsigned short* WF0 = (unsigned short*)alloc(16384 * 2);
    unsigned short* WF1 = (unsigned short*)alloc(16384 * 2);

    const int B1  = (E + 2047) / 2048;           // 2048-edge blocks
    const int NXH = (N * 8 + 255) / 256;         // x->H blocks (8 elems/thread)
    const int NH256 = (N + 255) / 256;           // buckets (one radix2 block each)
    const int EB4 = (E + 1023) / 1024;           // wfix blocks (4 edges/thread)
    const int NG = (N + GROWS - 1) / GROWS;      // gather blocks (512 thr)
    const int NM = (N + 63) / 64;                // gemm blocks (256 thr)

    // --- CSR build: count -> scan -> scatter -> group -> weight-pack ---
    hipMemsetAsync(gcount, 0, 256 * 32 * 4, stream);
    prep_kernel<<<B1 + 128 + NXH, 256, 0, stream>>>(dst, gcount, E, B1,
                                                    W0, W1, WF0, WF1, x, HA, N * 8);
    scan256_kernel<<<1, 256, 0, stream>>>(gcount, gbase, gcursor, E);
    bucket_kernel<<<B1, 256, 0, stream>>>(dst, src, gcursor, tmp32, E);
    radix2_kernel<<<NH256, 512, 0, stream>>>(gbase, tmp32, epack, dinv, pdeg, rowstart, N);
    wfix_kernel<<<EB4, 256, 0, stream>>>(epack, dinv, E);

    // --- layer 0: gathers fill HA slots 1..3, fused GEMM+bias+PReLU -> HB slot 0 (+ out init) ---
    gather_kernel<<<NG, 512, 0, stream>>>(HA + 0 * 64, HA + 1 * 64, rowstart, pdeg, dinv, epack, N);
    gather_kernel<<<NG, 512, 0, stream>>>(HA + 1 * 64, HA + 2 * 64, rowstart, pdeg, dinv, epack, N);
    gather_kernel<<<NG, 512, 0, stream>>>(HA + 2 * 64, HA + 3 * 64, rowstart, pdeg, dinv, epack, N);
    tag_gemm_kernel<2><<<NM, 256, 0, stream>>>(HA, WF0, b0, a0, nullptr, nullptr, bout,
                                               HB, (float*)d_out, N);

    // --- layer 1: gathers fill HB slots 1..3, fused GEMM+bias+PReLU+Wout-dot+pool -> out ---
    gather_kernel<<<NG, 512, 0, stream>>>(HB + 0 * 64, HB + 1 * 64, rowstart, pdeg, dinv, epack, N);
    gather_kernel<<<NG, 512, 0, stream>>>(HB + 1 * 64, HB + 2 * 64, rowstart, pdeg, dinv, epack, N);
    gather_kernel<<<NG, 512, 0, stream>>>(HB + 2 * 64, HB + 3 * 64, rowstart, pdeg, dinv, epack, N);
    tag_gemm_kernel<3><<<NM, 256, 0, stream>>>(HB, WF1, b1, a1, Wout, batch, bout,
                                               nullptr, (float*)d_out, N);
}